// Round 1
// baseline (65.021 us; speedup 1.0000x reference)
//
#include <hip/hip_runtime.h>

// P1 function-space evaluation on a regular 16x16 unit-square triangle mesh.
// Direct O(1) point location instead of the reference's O(512) search.
//
// Exact-semantics notes (verified against reference arithmetic):
//  * px*16 is exact (pow2 scale); fx = px*16 - i is exact (both are multiples
//    of 2^-19 < 16). These equal the reference's fp32 s/t inputs bit-for-bit.
//  * bbox is fp32: k/16 +- 1e-10 rounds to exactly k/16 for k>=1, and the bbox
//    test is strict => a point exactly on an interior grid line k/16 (k=1..15)
//    is in NO bbox => hit=False => output 0. k=0 keeps the -1e-10 margin.
//  * Diagonal tie fx==fy: both triangles contain the point; reference argmax
//    picks the larger triangle index = upper batch => choose upper on ties.

#define TOLF 1e-10f

__device__ __forceinline__ void eval_pt(float px, float py,
                                        const float* __restrict__ wx,
                                        const float* __restrict__ wy,
                                        float& ox, float& oy) {
    float sx = px * 16.0f;
    float sy = py * 16.0f;
    int i = (int)floorf(sx);
    int j = (int)floorf(sy);
    i = i < 0 ? 0 : (i > 15 ? 15 : i);
    j = j < 0 ? 0 : (j > 15 ? 15 : j);
    float fx = sx - (float)i;   // exact
    float fy = sy - (float)j;   // exact
    // Reference bbox semantics: strict compares vs fp32-rounded k/16 bounds.
    bool miss = ((fx == 0.0f) && (i > 0)) || ((fy == 0.0f) && (j > 0));

    float s, t;
    int d0 = i * 17 + j;  // v(i,j) = i*(n+1)+j
    int d1, d2;
    if (fy - fx > -TOLF) {
        // upper triangle (v00, v11, v01): larger index -> wins argmax ties
        s = fx;      t = fy - fx;
        d1 = d0 + 18; d2 = d0 + 1;
    } else {
        // lower triangle (v00, v10, v11)
        s = fx - fy; t = fy;
        d1 = d0 + 17; d2 = d0 + 18;
    }
    float b0 = 1.0f - s - t;
    float rx = b0 * wx[d0] + s * wx[d1] + t * wx[d2];
    float ry = b0 * wy[d0] + s * wy[d1] + t * wy[d2];
    ox = miss ? 0.0f : rx;
    oy = miss ? 0.0f : ry;
}

__global__ void __launch_bounds__(256)
p1_eval_kernel(const float4* __restrict__ x,
               const float* __restrict__ wx,
               const float* __restrict__ wy,
               float4* __restrict__ out, int npairs) {
    int idx = blockIdx.x * blockDim.x + threadIdx.x;
    if (idx >= npairs) return;
    float4 p = x[idx];   // two points: (p.x,p.y), (p.z,p.w)
    float4 r;
    eval_pt(p.x, p.y, wx, wy, r.x, r.y);
    eval_pt(p.z, p.w, wx, wy, r.z, r.w);
    out[idx] = r;
}

extern "C" void kernel_launch(void* const* d_in, const int* in_sizes, int n_in,
                              void* d_out, int out_size, void* d_ws, size_t ws_size,
                              hipStream_t stream) {
    // setup_inputs order: x, weight_x, weight_y, Minv, A, bbox, dofs
    const float4* x  = (const float4*)d_in[0];
    const float*  wx = (const float*)d_in[1];
    const float*  wy = (const float*)d_in[2];
    float4* out = (float4*)d_out;

    int npairs = in_sizes[0] / 4;  // 2 points (4 floats) per thread
    int block = 256;
    int grid = (npairs + block - 1) / block;
    p1_eval_kernel<<<grid, block, 0, stream>>>(x, wx, wy, out, npairs);
}

// Round 2
// 64.876 us; speedup vs baseline: 1.0022x; 1.0022x over previous
//
#include <hip/hip_runtime.h>

// P1 function-space evaluation on a regular 16x16 unit-square triangle mesh.
// Direct O(1) point location instead of the reference's O(512) search.
//
// Exact-semantics notes (verified against reference arithmetic):
//  * px*16 is exact (pow2 scale); fx = px*16 - i is exact (both are multiples
//    of 2^-19 < 16). These equal the reference's fp32 s/t inputs bit-for-bit.
//  * bbox is fp32: k/16 +- 1e-10 rounds to exactly k/16 for k>=1, and the bbox
//    test is strict => a point exactly on an interior grid line k/16 (k=1..15)
//    is in NO bbox => hit=False => output 0. k=0 keeps the -1e-10 margin.
//  * Diagonal tie fx==fy: both triangles contain the point; reference argmax
//    picks the larger triangle index = upper batch => choose upper on ties.
//
// R1: one point per thread (65536 threads, 256 blocks -> all 256 CUs, 2x waves
// vs R0's 128 blocks). Tests whether dur_us responds to kernel time at all —
// rocprof shows the harness's 268 MB d_ws poison (40.9 us) dominates.

#define TOLF 1e-10f

__device__ __forceinline__ void eval_pt(float px, float py,
                                        const float* __restrict__ wx,
                                        const float* __restrict__ wy,
                                        float& ox, float& oy) {
    float sx = px * 16.0f;
    float sy = py * 16.0f;
    int i = (int)floorf(sx);
    int j = (int)floorf(sy);
    i = i < 0 ? 0 : (i > 15 ? 15 : i);
    j = j < 0 ? 0 : (j > 15 ? 15 : j);
    float fx = sx - (float)i;   // exact
    float fy = sy - (float)j;   // exact
    // Reference bbox semantics: strict compares vs fp32-rounded k/16 bounds.
    bool miss = ((fx == 0.0f) && (i > 0)) || ((fy == 0.0f) && (j > 0));

    float s, t;
    int d0 = i * 17 + j;  // v(i,j) = i*(n+1)+j
    int d1, d2;
    if (fy - fx > -TOLF) {
        // upper triangle (v00, v11, v01): larger index -> wins argmax ties
        s = fx;      t = fy - fx;
        d1 = d0 + 18; d2 = d0 + 1;
    } else {
        // lower triangle (v00, v10, v11)
        s = fx - fy; t = fy;
        d1 = d0 + 17; d2 = d0 + 18;
    }
    float b0 = 1.0f - s - t;
    float rx = b0 * wx[d0] + s * wx[d1] + t * wx[d2];
    float ry = b0 * wy[d0] + s * wy[d1] + t * wy[d2];
    ox = miss ? 0.0f : rx;
    oy = miss ? 0.0f : ry;
}

__global__ void __launch_bounds__(256)
p1_eval_kernel(const float2* __restrict__ x,
               const float* __restrict__ wx,
               const float* __restrict__ wy,
               float2* __restrict__ out, int npts) {
    int idx = blockIdx.x * blockDim.x + threadIdx.x;
    if (idx >= npts) return;
    float2 p = x[idx];   // one point per thread
    float2 r;
    eval_pt(p.x, p.y, wx, wy, r.x, r.y);
    out[idx] = r;
}

extern "C" void kernel_launch(void* const* d_in, const int* in_sizes, int n_in,
                              void* d_out, int out_size, void* d_ws, size_t ws_size,
                              hipStream_t stream) {
    // setup_inputs order: x, weight_x, weight_y, Minv, A, bbox, dofs
    const float2* x  = (const float2*)d_in[0];
    const float*  wx = (const float*)d_in[1];
    const float*  wy = (const float*)d_in[2];
    float2* out = (float2*)d_out;

    int npts = in_sizes[0] / 2;  // one point (2 floats) per thread
    int block = 256;
    int grid = (npts + block - 1) / block;
    p1_eval_kernel<<<grid, block, 0, stream>>>(x, wx, wy, out, npts);
}